// Round 1
// baseline (1772.422 us; speedup 1.0000x reference)
//
#include <hip/hip_runtime.h>

#define N_NODES   100000
#define N_EDGES   1600000
#define D         64
#define N_TARGETS 100
#define N_GRAPHS  512

// ---------------- small utility kernels ----------------

__global__ void k_zero(float* __restrict__ p, int n) {
    int i = blockIdx.x * blockDim.x + threadIdx.x;
    if (i < n) p[i] = 0.0f;
}

__global__ void k_count_deg(const int* __restrict__ dst, float* __restrict__ deg, int E) {
    int e = blockIdx.x * blockDim.x + threadIdx.x;
    if (e < E) atomicAdd(&deg[dst[e]], 1.0f);
}

__global__ void k_finalize_dinv(float* __restrict__ deg, int n) {
    int i = blockIdx.x * blockDim.x + threadIdx.x;
    if (i < n) deg[i] = rsqrtf(deg[i] + 1.0f);   // +1 for self-loop
}

// ---------------- dense matmul: Y = (relu?)X @ W ----------------
// Block = 256 threads = 4 rows x 64 cols. W (64x64 = 16KB) staged in LDS.
// X row element broadcast via __shfl (register-only, no repeated global reads).
__global__ void k_mm(const float* __restrict__ X, const float* __restrict__ W,
                     float* __restrict__ Y, int n, int relu_in) {
    __shared__ float Ws[D * D];
    int tid = threadIdx.x;
#pragma unroll
    for (int i = 0; i < (D * D) / 256; ++i)
        Ws[tid + 256 * i] = W[tid + 256 * i];
    __syncthreads();

    int lane = tid & 63;
    int row  = blockIdx.x * 4 + (tid >> 6);
    if (row >= n) return;

    float xv = X[(size_t)row * D + lane];
    if (relu_in) xv = fmaxf(xv, 0.0f);

    float acc = 0.0f;
#pragma unroll
    for (int k = 0; k < D; ++k) {
        float xk = __shfl(xv, k, 64);
        acc = fmaf(xk, Ws[k * D + lane], acc);   // bank: lane%32 -> 2-way, free
    }
    Y[(size_t)row * D + lane] = acc;
}

// ---------------- AGG init: AGG = H * dinv^2 + b (self-loop + bias fused) ----
__global__ void k_self_bias(const float* __restrict__ H, const float* __restrict__ dinv,
                            const float* __restrict__ b, float* __restrict__ AGG, int n64) {
    int idx = blockIdx.x * blockDim.x + threadIdx.x;
    if (idx >= n64) return;
    int i = idx >> 6;
    int d = idx & 63;
    float di = dinv[i];
    AGG[idx] = fmaf(H[idx], di * di, b[d]);
}

// ---------------- edge scatter: AGG[dst] += H[src] * dinv[src]*dinv[dst] ----
// One wave (64 lanes) per edge; lane = feature. src/dst/dinv loads are
// wave-uniform (scalarized by the compiler); H gather + atomics coalesced.
__global__ void k_scatter(const float* __restrict__ H, const int* __restrict__ src,
                          const int* __restrict__ dst, const float* __restrict__ dinv,
                          float* __restrict__ AGG, int E) {
    int e    = blockIdx.x * (blockDim.x >> 6) + (threadIdx.x >> 6);
    int lane = threadIdx.x & 63;
    if (e >= E) return;
    int s = src[e], d = dst[e];
    float nrm = dinv[s] * dinv[d];
    float v = H[(size_t)s * D + lane] * nrm;
    atomicAdd(&AGG[(size_t)d * D + lane], v);
}

// ---------------- pooling: pooled[g] += H[i], counts[g] += 1 ----------------
__global__ void k_pool(const float* __restrict__ H, const int* __restrict__ seg,
                       float* __restrict__ pooled, float* __restrict__ counts, int n) {
    int i    = blockIdx.x * (blockDim.x >> 6) + (threadIdx.x >> 6);
    int lane = threadIdx.x & 63;
    if (i >= n) return;
    int g = seg[i];
    atomicAdd(&pooled[(size_t)g * D + lane], H[(size_t)i * D + lane]);
    if (lane == 0) atomicAdd(&counts[g], 1.0f);
}

// ---------------- head: out[g] = (pooled[g]/count[g]) @ Wout + bout ----------
__global__ void k_out(const float* __restrict__ pooled, const float* __restrict__ counts,
                      const float* __restrict__ Wout, const float* __restrict__ bout,
                      float* __restrict__ out) {
    __shared__ float prow[D];
    int g = blockIdx.x;
    int t = threadIdx.x;
    if (t < D) prow[t] = pooled[(size_t)g * D + t] / fmaxf(counts[g], 1.0f);
    __syncthreads();
    if (t < N_TARGETS) {
        float acc = bout[t];
#pragma unroll
        for (int k = 0; k < D; ++k)
            acc = fmaf(prow[k], Wout[k * N_TARGETS + t], acc);
        out[g * N_TARGETS + t] = acc;
    }
}

// ---------------- driver ----------------

extern "C" void kernel_launch(void* const* d_in, const int* in_sizes, int n_in,
                              void* d_out, int out_size, void* d_ws, size_t ws_size,
                              hipStream_t stream) {
    const float* x    = (const float*)d_in[0];
    const float* W1   = (const float*)d_in[1];
    const float* b1   = (const float*)d_in[2];
    const float* W2   = (const float*)d_in[3];
    const float* b2   = (const float*)d_in[4];
    const float* W3   = (const float*)d_in[5];
    const float* b3   = (const float*)d_in[6];
    const float* Wout = (const float*)d_in[7];
    const float* bout = (const float*)d_in[8];
    const int*   eidx = (const int*)d_in[9];
    const int*   seg  = (const int*)d_in[10];
    const int* src = eidx;            // edge_index[0]
    const int* dst = eidx + N_EDGES;  // edge_index[1]

    float* ws     = (float*)d_ws;
    float* bufA   = ws;                       // N*D  (h = x @ W)
    float* bufB   = bufA + (size_t)N_NODES*D; // N*D  (agg accumulator)
    float* dinv   = bufB + (size_t)N_NODES*D; // N
    float* pooled = dinv + N_NODES;           // N_GRAPHS*D
    float* counts = pooled + N_GRAPHS * D;    // N_GRAPHS (contiguous after pooled)
    float* out    = (float*)d_out;

    const int ND = N_NODES * D;

    // degrees -> dinv (dst-only, shared by all 3 layers)
    k_zero<<<(N_NODES + 255) / 256, 256, 0, stream>>>(dinv, N_NODES);
    k_count_deg<<<(N_EDGES + 255) / 256, 256, 0, stream>>>(dst, dinv, N_EDGES);
    k_finalize_dinv<<<(N_NODES + 255) / 256, 256, 0, stream>>>(dinv, N_NODES);

    // ---- layer 1 ----
    k_mm<<<(N_NODES + 3) / 4, 256, 0, stream>>>(x, W1, bufA, N_NODES, 0);
    k_self_bias<<<(ND + 255) / 256, 256, 0, stream>>>(bufA, dinv, b1, bufB, ND);
    k_scatter<<<(N_EDGES + 3) / 4, 256, 0, stream>>>(bufA, src, dst, dinv, bufB, N_EDGES);

    // ---- layer 2 (input = relu(bufB)) ----
    k_mm<<<(N_NODES + 3) / 4, 256, 0, stream>>>(bufB, W2, bufA, N_NODES, 1);
    k_self_bias<<<(ND + 255) / 256, 256, 0, stream>>>(bufA, dinv, b2, bufB, ND);
    k_scatter<<<(N_EDGES + 3) / 4, 256, 0, stream>>>(bufA, src, dst, dinv, bufB, N_EDGES);

    // ---- layer 3 (input = relu(bufB), no output relu) ----
    k_mm<<<(N_NODES + 3) / 4, 256, 0, stream>>>(bufB, W3, bufA, N_NODES, 1);
    k_self_bias<<<(ND + 255) / 256, 256, 0, stream>>>(bufA, dinv, b3, bufB, ND);
    k_scatter<<<(N_EDGES + 3) / 4, 256, 0, stream>>>(bufA, src, dst, dinv, bufB, N_EDGES);

    // ---- mean pool + head ----
    k_zero<<<(N_GRAPHS * D + N_GRAPHS + 255) / 256, 256, 0, stream>>>(pooled, N_GRAPHS * D + N_GRAPHS);
    k_pool<<<(N_NODES + 3) / 4, 256, 0, stream>>>(bufB, seg, pooled, counts, N_NODES);
    k_out<<<N_GRAPHS, 128, 0, stream>>>(pooled, counts, Wout, bout, out);
}

// Round 2
// 1215.206 us; speedup vs baseline: 1.4585x; 1.4585x over previous
//
#include <hip/hip_runtime.h>

#define N_NODES   100000
#define N_EDGES   1600000
#define D         64
#define N_TARGETS 100
#define N_GRAPHS  512

// ---------------- utility ----------------

__global__ void k_zero_i(int* __restrict__ p, int n) {
    int i = blockIdx.x * blockDim.x + threadIdx.x;
    if (i < n) p[i] = 0;
}
__global__ void k_zero_f(float* __restrict__ p, int n) {
    int i = blockIdx.x * blockDim.x + threadIdx.x;
    if (i < n) p[i] = 0.0f;
}

// ---------------- CSR build ----------------

__global__ void k_deg(const int* __restrict__ dst, int* __restrict__ deg) {
    int e = blockIdx.x * blockDim.x + threadIdx.x;
    if (e < N_EDGES) atomicAdd(&deg[dst[e]], 1);
}

__global__ void k_dinv(const int* __restrict__ deg, float* __restrict__ dinv) {
    int i = blockIdx.x * blockDim.x + threadIdx.x;
    if (i < N_NODES) dinv[i] = rsqrtf((float)deg[i] + 1.0f);  // +1 self-loop
}

// exclusive scan of deg within each 256-block; block totals -> bsum
__global__ void k_scan1(const int* __restrict__ deg, int* __restrict__ base,
                        int* __restrict__ bsum) {
    __shared__ int s[256];
    int t = threadIdx.x, i = blockIdx.x * 256 + t;
    int v = (i < N_NODES) ? deg[i] : 0;
    s[t] = v;
    __syncthreads();
    for (int off = 1; off < 256; off <<= 1) {
        int x = (t >= off) ? s[t - off] : 0;
        __syncthreads();
        s[t] += x;
        __syncthreads();
    }
    if (i < N_NODES) base[i] = s[t] - v;      // exclusive within block
    if (t == 255) bsum[blockIdx.x] = s[255];  // block total
}

// exclusive scan of block sums (single block, 512 threads >= 391 blocks)
__global__ void k_scan2(int* __restrict__ bsum, int nb) {
    __shared__ int s[512];
    int t = threadIdx.x;
    int v = (t < nb) ? bsum[t] : 0;
    s[t] = v;
    __syncthreads();
    for (int off = 1; off < 512; off <<= 1) {
        int x = (t >= off) ? s[t - off] : 0;
        __syncthreads();
        s[t] += x;
        __syncthreads();
    }
    if (t < nb) bsum[t] = s[t] - v;
}

// add block offsets; zero cursor (reuses deg buffer); set base[N]=E
__global__ void k_scan3(int* __restrict__ base, const int* __restrict__ bsum,
                        int* __restrict__ cursor) {
    int i = blockIdx.x * blockDim.x + threadIdx.x;
    if (i < N_NODES) {
        base[i] += bsum[i >> 8];
        cursor[i] = 0;
    }
    if (i == 0) base[N_NODES] = N_EDGES;
}

__global__ void k_fill(const int* __restrict__ src, const int* __restrict__ dst,
                       const int* __restrict__ base, int* __restrict__ cursor,
                       int* __restrict__ esrc) {
    int e = blockIdx.x * blockDim.x + threadIdx.x;
    if (e < N_EDGES) {
        int d = dst[e];
        int pos = base[d] + atomicAdd(&cursor[d], 1);
        esrc[pos] = src[e];
    }
}

// ---------------- matmul: Y[row] = (relu?)X[row] @ W * dinv[row] ----------------
// Wave = 64 lanes = 64 output cols; lane holds W column in 64 VGPRs.
// 8 rows per wave; X read via wave-uniform float4 broadcast loads.
__global__ void __launch_bounds__(256)
k_mm(const float* __restrict__ X, const float* __restrict__ W,
     const float* __restrict__ dinv, float* __restrict__ Y, int relu) {
    int lane = threadIdx.x & 63;
    int wid  = threadIdx.x >> 6;
    int row0 = blockIdx.x * 32 + wid * 8;  // 100000 = 3125 blocks * 32 rows, exact

    float Wc[64];
#pragma unroll
    for (int k = 0; k < 64; ++k) Wc[k] = W[k * 64 + lane];

    float acc[8];
#pragma unroll
    for (int r = 0; r < 8; ++r) acc[r] = 0.0f;

#pragma unroll
    for (int j = 0; j < 16; ++j) {
#pragma unroll
        for (int r = 0; r < 8; ++r) {
            float4 xv = ((const float4*)(X + (size_t)(row0 + r) * D))[j];
            if (relu) {
                xv.x = fmaxf(xv.x, 0.0f); xv.y = fmaxf(xv.y, 0.0f);
                xv.z = fmaxf(xv.z, 0.0f); xv.w = fmaxf(xv.w, 0.0f);
            }
            acc[r] = fmaf(xv.x, Wc[4 * j + 0], acc[r]);
            acc[r] = fmaf(xv.y, Wc[4 * j + 1], acc[r]);
            acc[r] = fmaf(xv.z, Wc[4 * j + 2], acc[r]);
            acc[r] = fmaf(xv.w, Wc[4 * j + 3], acc[r]);
        }
    }
#pragma unroll
    for (int r = 0; r < 8; ++r)
        Y[(size_t)(row0 + r) * D + lane] = acc[r] * dinv[row0 + r];
}

// ---------------- pull aggregation ----------------
// H is pre-scaled by dinv[src]; AGG[i] = (H[i] + sum_{s in in(i)} H[s]) * dinv[i] + b
// Wave per node, lane = feature. Edge srcs loaded coalesced, shfl-broadcast,
// gathers unrolled x4 for memory-level parallelism. No atomics.
__global__ void __launch_bounds__(256)
k_pull(const float* __restrict__ H, const int* __restrict__ esrc,
       const int* __restrict__ base, const float* __restrict__ dinv,
       const float* __restrict__ b, float* __restrict__ AGG) {
    int i    = blockIdx.x * 4 + (threadIdx.x >> 6);  // 25000 blocks * 4 = exact
    int lane = threadIdx.x & 63;
    int s0 = base[i], s1 = base[i + 1];
    float di = dinv[i];
    float bl = b[lane];
    float acc = H[(size_t)i * D + lane];  // self-loop term (pre-scaled)
    int p = s0;
    while (p < s1) {
        int cnt = s1 - p;
        if (cnt > 64) cnt = 64;
        int ed = (lane < cnt) ? esrc[p + lane] : 0;
        int j = 0;
        for (; j + 4 <= cnt; j += 4) {
            int a0 = __shfl(ed, j, 64), a1 = __shfl(ed, j + 1, 64);
            int a2 = __shfl(ed, j + 2, 64), a3 = __shfl(ed, j + 3, 64);
            float v0 = H[(size_t)a0 * D + lane];
            float v1 = H[(size_t)a1 * D + lane];
            float v2 = H[(size_t)a2 * D + lane];
            float v3 = H[(size_t)a3 * D + lane];
            acc += (v0 + v1) + (v2 + v3);
        }
        for (; j < cnt; ++j)
            acc += H[(size_t)__shfl(ed, j, 64) * D + lane];
        p += cnt;
    }
    AGG[(size_t)i * D + lane] = fmaf(acc, di, bl);
}

// layer-3 variant: fuse graph mean-pool accumulation (atomics into 128KB buffer)
__global__ void __launch_bounds__(256)
k_pull_pool(const float* __restrict__ H, const int* __restrict__ esrc,
            const int* __restrict__ base, const float* __restrict__ dinv,
            const float* __restrict__ b, const int* __restrict__ seg,
            float* __restrict__ pooled) {
    int i    = blockIdx.x * 4 + (threadIdx.x >> 6);
    int lane = threadIdx.x & 63;
    int s0 = base[i], s1 = base[i + 1];
    float di = dinv[i];
    float bl = b[lane];
    float acc = H[(size_t)i * D + lane];
    int p = s0;
    while (p < s1) {
        int cnt = s1 - p;
        if (cnt > 64) cnt = 64;
        int ed = (lane < cnt) ? esrc[p + lane] : 0;
        int j = 0;
        for (; j + 4 <= cnt; j += 4) {
            int a0 = __shfl(ed, j, 64), a1 = __shfl(ed, j + 1, 64);
            int a2 = __shfl(ed, j + 2, 64), a3 = __shfl(ed, j + 3, 64);
            float v0 = H[(size_t)a0 * D + lane];
            float v1 = H[(size_t)a1 * D + lane];
            float v2 = H[(size_t)a2 * D + lane];
            float v3 = H[(size_t)a3 * D + lane];
            acc += (v0 + v1) + (v2 + v3);
        }
        for (; j < cnt; ++j)
            acc += H[(size_t)__shfl(ed, j, 64) * D + lane];
        p += cnt;
    }
    int g = seg[i];
    atomicAdd(&pooled[(size_t)g * D + lane], fmaf(acc, di, bl));
}

__global__ void k_counts(const int* __restrict__ seg, float* __restrict__ counts) {
    int i = blockIdx.x * blockDim.x + threadIdx.x;
    if (i < N_NODES) atomicAdd(&counts[seg[i]], 1.0f);
}

// ---------------- head: out[g] = (pooled[g]/count[g]) @ Wout + bout ----------
__global__ void k_out(const float* __restrict__ pooled, const float* __restrict__ counts,
                      const float* __restrict__ Wout, const float* __restrict__ bout,
                      float* __restrict__ out) {
    __shared__ float prow[D];
    int g = blockIdx.x;
    int t = threadIdx.x;
    if (t < D) prow[t] = pooled[(size_t)g * D + t] / fmaxf(counts[g], 1.0f);
    __syncthreads();
    if (t < N_TARGETS) {
        float acc = bout[t];
#pragma unroll
        for (int k = 0; k < D; ++k)
            acc = fmaf(prow[k], Wout[k * N_TARGETS + t], acc);
        out[g * N_TARGETS + t] = acc;
    }
}

// ---------------- driver ----------------

extern "C" void kernel_launch(void* const* d_in, const int* in_sizes, int n_in,
                              void* d_out, int out_size, void* d_ws, size_t ws_size,
                              hipStream_t stream) {
    const float* x    = (const float*)d_in[0];
    const float* W1   = (const float*)d_in[1];
    const float* b1   = (const float*)d_in[2];
    const float* W2   = (const float*)d_in[3];
    const float* b2   = (const float*)d_in[4];
    const float* W3   = (const float*)d_in[5];
    const float* b3   = (const float*)d_in[6];
    const float* Wout = (const float*)d_in[7];
    const float* bout = (const float*)d_in[8];
    const int*   eidx = (const int*)d_in[9];
    const int*   seg  = (const int*)d_in[10];
    const int* src = eidx;            // edge_index[0]
    const int* dst = eidx + N_EDGES;  // edge_index[1]
    float* out = (float*)d_out;

    // workspace layout (all 4B elems): total ~58.9 MB
    float* bufA   = (float*)d_ws;                  // 6,400,000
    float* bufB   = bufA + (size_t)N_NODES * D;    // 6,400,000
    int*   esrc   = (int*)(bufB + (size_t)N_NODES * D);  // 1,600,000
    float* dinv   = (float*)(esrc + N_EDGES);      // 100,000
    int*   degc   = (int*)(dinv + N_NODES);        // 100,000 (deg, then cursor)
    int*   base   = degc + N_NODES;                // 100,001 (+pad)
    int*   bsum   = base + N_NODES + 4;            // 512
    float* pooled = (float*)(bsum + 512);          // 32,768
    float* counts = pooled + N_GRAPHS * D;         // 512

    const int NB = (N_NODES + 255) / 256;  // 391

    // ---- CSR build (per-call; edge_index constant but no caching allowed) ----
    k_zero_i<<<NB, 256, 0, stream>>>(degc, N_NODES);
    k_deg<<<N_EDGES / 256, 256, 0, stream>>>(dst, degc);
    k_dinv<<<NB, 256, 0, stream>>>(degc, dinv);
    k_scan1<<<NB, 256, 0, stream>>>(degc, base, bsum);
    k_scan2<<<1, 512, 0, stream>>>(bsum, NB);
    k_scan3<<<NB, 256, 0, stream>>>(base, bsum, degc);
    k_fill<<<N_EDGES / 256, 256, 0, stream>>>(src, dst, base, degc, esrc);

    // ---- 3 GCN layers ----
    k_mm<<<N_NODES / 32, 256, 0, stream>>>(x, W1, dinv, bufA, 0);
    k_pull<<<N_NODES / 4, 256, 0, stream>>>(bufA, esrc, base, dinv, b1, bufB);
    k_mm<<<N_NODES / 32, 256, 0, stream>>>(bufB, W2, dinv, bufA, 1);
    k_pull<<<N_NODES / 4, 256, 0, stream>>>(bufA, esrc, base, dinv, b2, bufB);
    k_mm<<<N_NODES / 32, 256, 0, stream>>>(bufB, W3, dinv, bufA, 1);

    // ---- layer-3 pull fused with mean-pool accumulation ----
    k_zero_f<<<(N_GRAPHS * D + N_GRAPHS + 255) / 256, 256, 0, stream>>>(pooled, N_GRAPHS * D + N_GRAPHS);
    k_counts<<<NB, 256, 0, stream>>>(seg, counts);
    k_pull_pool<<<N_NODES / 4, 256, 0, stream>>>(bufA, esrc, base, dinv, b3, seg, pooled);

    k_out<<<N_GRAPHS, 128, 0, stream>>>(pooled, counts, Wout, bout, out);
}

// Round 3
// 699.586 us; speedup vs baseline: 2.5335x; 1.7370x over previous
//
#include <hip/hip_runtime.h>

#define N_NODES   100000
#define N_EDGES   1600000
#define D         64
#define N_TARGETS 100
#define N_GRAPHS  512

// ---------------- utility ----------------

__global__ void k_zero_i(int* __restrict__ p, int n) {
    int i = blockIdx.x * blockDim.x + threadIdx.x;
    if (i < n) p[i] = 0;
}
__global__ void k_zero_f(float* __restrict__ p, int n) {
    int i = blockIdx.x * blockDim.x + threadIdx.x;
    if (i < n) p[i] = 0.0f;
}

// ---------------- CSR build ----------------

__global__ void k_deg(const int* __restrict__ dst, int* __restrict__ deg) {
    int e = blockIdx.x * blockDim.x + threadIdx.x;
    if (e < N_EDGES) atomicAdd(&deg[dst[e]], 1);
}

__global__ void k_dinv(const int* __restrict__ deg, float* __restrict__ dinv) {
    int i = blockIdx.x * blockDim.x + threadIdx.x;
    if (i < N_NODES) dinv[i] = rsqrtf((float)deg[i] + 1.0f);  // +1 self-loop
}

// exclusive scan of deg within each 256-block; block totals -> bsum
__global__ void k_scan1(const int* __restrict__ deg, int* __restrict__ base,
                        int* __restrict__ bsum) {
    __shared__ int s[256];
    int t = threadIdx.x, i = blockIdx.x * 256 + t;
    int v = (i < N_NODES) ? deg[i] : 0;
    s[t] = v;
    __syncthreads();
    for (int off = 1; off < 256; off <<= 1) {
        int x = (t >= off) ? s[t - off] : 0;
        __syncthreads();
        s[t] += x;
        __syncthreads();
    }
    if (i < N_NODES) base[i] = s[t] - v;      // exclusive within block
    if (t == 255) bsum[blockIdx.x] = s[255];  // block total
}

// exclusive scan of block sums (single block, 512 threads >= 391 blocks)
__global__ void k_scan2(int* __restrict__ bsum, int nb) {
    __shared__ int s[512];
    int t = threadIdx.x;
    int v = (t < nb) ? bsum[t] : 0;
    s[t] = v;
    __syncthreads();
    for (int off = 1; off < 512; off <<= 1) {
        int x = (t >= off) ? s[t - off] : 0;
        __syncthreads();
        s[t] += x;
        __syncthreads();
    }
    if (t < nb) bsum[t] = s[t] - v;
}

// add block offsets; zero cursor (reuses deg buffer); set base[N]=E
__global__ void k_scan3(int* __restrict__ base, const int* __restrict__ bsum,
                        int* __restrict__ cursor) {
    int i = blockIdx.x * blockDim.x + threadIdx.x;
    if (i < N_NODES) {
        base[i] += bsum[i >> 8];
        cursor[i] = 0;
    }
    if (i == 0) base[N_NODES] = N_EDGES;
}

__global__ void k_fill(const int* __restrict__ src, const int* __restrict__ dst,
                       const int* __restrict__ base, int* __restrict__ cursor,
                       int* __restrict__ esrc) {
    int e = blockIdx.x * blockDim.x + threadIdx.x;
    if (e < N_EDGES) {
        int d = dst[e];
        int pos = base[d] + atomicAdd(&cursor[d], 1);
        esrc[pos] = src[e];
    }
}

// ---------------- matmul: Y[row] = (relu?)X[row] @ W * dinv[row] ----------------
// 64x64 output tile per 256-thread block; X-tile + W staged in LDS (pad +4
// breaks the 4-row bank alias to 2-way = free); each thread computes a 4x4
// block via ds_read_b128 fragments. ~60 VGPR, no spills.
__global__ void __launch_bounds__(256)
k_mm(const float* __restrict__ X, const float* __restrict__ W,
     const float* __restrict__ dinv, float* __restrict__ Y, int relu) {
    __shared__ float Xs[64][68];
    __shared__ float Ws[64][68];
    int tid = threadIdx.x;
    int r0  = blockIdx.x * 64;
    {
        int lr = tid >> 4;           // 0..15
        int lc = (tid & 15) * 4;     // 0,4,..,60
#pragma unroll
        for (int i = 0; i < 4; ++i) {
            int row = lr + 16 * i;
            *(float4*)&Ws[row][lc] = *(const float4*)(W + row * 64 + lc);
            int gr = r0 + row;
            if (gr < N_NODES) {
                float4 xv = *(const float4*)(X + (size_t)gr * 64 + lc);
                if (relu) {
                    xv.x = fmaxf(xv.x, 0.0f); xv.y = fmaxf(xv.y, 0.0f);
                    xv.z = fmaxf(xv.z, 0.0f); xv.w = fmaxf(xv.w, 0.0f);
                }
                *(float4*)&Xs[row][lc] = xv;
            }
        }
    }
    __syncthreads();

    int tx = (tid & 15) * 4;  // output col base
    int ty = (tid >> 4) * 4;  // output row base (within tile)
    float acc[4][4] = {{0.f}};

#pragma unroll
    for (int kk = 0; kk < 16; ++kk) {
        float4 a[4], w[4];
#pragma unroll
        for (int r = 0; r < 4; ++r) a[r] = *(float4*)&Xs[ty + r][kk * 4];
#pragma unroll
        for (int k = 0; k < 4; ++k) w[k] = *(float4*)&Ws[kk * 4 + k][tx];
#pragma unroll
        for (int r = 0; r < 4; ++r) {
#pragma unroll
            for (int k = 0; k < 4; ++k) {
                float av = ((const float*)&a[r])[k];
                acc[r][0] = fmaf(av, w[k].x, acc[r][0]);
                acc[r][1] = fmaf(av, w[k].y, acc[r][1]);
                acc[r][2] = fmaf(av, w[k].z, acc[r][2]);
                acc[r][3] = fmaf(av, w[k].w, acc[r][3]);
            }
        }
    }

#pragma unroll
    for (int r = 0; r < 4; ++r) {
        int gr = r0 + ty + r;
        if (gr < N_NODES) {
            float di = dinv[gr];
            float4 o = { acc[r][0] * di, acc[r][1] * di, acc[r][2] * di, acc[r][3] * di };
            *(float4*)(Y + (size_t)gr * 64 + tx) = o;
        }
    }
}

// ---------------- pull aggregation ----------------
// H is pre-scaled by dinv[src]; AGG[i] = (H[i] + sum_{s in in(i)} H[s]) * dinv[i] + b
// Wave per node, lane = feature. Edge srcs loaded coalesced, shfl-broadcast,
// gathers unrolled x4 for memory-level parallelism. No atomics.
__global__ void __launch_bounds__(256)
k_pull(const float* __restrict__ H, const int* __restrict__ esrc,
       const int* __restrict__ base, const float* __restrict__ dinv,
       const float* __restrict__ b, float* __restrict__ AGG) {
    int i    = blockIdx.x * 4 + (threadIdx.x >> 6);  // 25000 blocks * 4 = exact
    int lane = threadIdx.x & 63;
    int s0 = base[i], s1 = base[i + 1];
    float di = dinv[i];
    float bl = b[lane];
    float acc = H[(size_t)i * D + lane];  // self-loop term (pre-scaled)
    int p = s0;
    while (p < s1) {
        int cnt = s1 - p;
        if (cnt > 64) cnt = 64;
        int ed = (lane < cnt) ? esrc[p + lane] : 0;
        int j = 0;
        for (; j + 4 <= cnt; j += 4) {
            int a0 = __shfl(ed, j, 64), a1 = __shfl(ed, j + 1, 64);
            int a2 = __shfl(ed, j + 2, 64), a3 = __shfl(ed, j + 3, 64);
            float v0 = H[(size_t)a0 * D + lane];
            float v1 = H[(size_t)a1 * D + lane];
            float v2 = H[(size_t)a2 * D + lane];
            float v3 = H[(size_t)a3 * D + lane];
            acc += (v0 + v1) + (v2 + v3);
        }
        for (; j < cnt; ++j)
            acc += H[(size_t)__shfl(ed, j, 64) * D + lane];
        p += cnt;
    }
    AGG[(size_t)i * D + lane] = fmaf(acc, di, bl);
}

// layer-3 variant: fuse graph mean-pool accumulation (atomics into 128KB buffer)
__global__ void __launch_bounds__(256)
k_pull_pool(const float* __restrict__ H, const int* __restrict__ esrc,
            const int* __restrict__ base, const float* __restrict__ dinv,
            const float* __restrict__ b, const int* __restrict__ seg,
            float* __restrict__ pooled) {
    int i    = blockIdx.x * 4 + (threadIdx.x >> 6);
    int lane = threadIdx.x & 63;
    int s0 = base[i], s1 = base[i + 1];
    float di = dinv[i];
    float bl = b[lane];
    float acc = H[(size_t)i * D + lane];
    int p = s0;
    while (p < s1) {
        int cnt = s1 - p;
        if (cnt > 64) cnt = 64;
        int ed = (lane < cnt) ? esrc[p + lane] : 0;
        int j = 0;
        for (; j + 4 <= cnt; j += 4) {
            int a0 = __shfl(ed, j, 64), a1 = __shfl(ed, j + 1, 64);
            int a2 = __shfl(ed, j + 2, 64), a3 = __shfl(ed, j + 3, 64);
            float v0 = H[(size_t)a0 * D + lane];
            float v1 = H[(size_t)a1 * D + lane];
            float v2 = H[(size_t)a2 * D + lane];
            float v3 = H[(size_t)a3 * D + lane];
            acc += (v0 + v1) + (v2 + v3);
        }
        for (; j < cnt; ++j)
            acc += H[(size_t)__shfl(ed, j, 64) * D + lane];
        p += cnt;
    }
    int g = seg[i];
    atomicAdd(&pooled[(size_t)g * D + lane], fmaf(acc, di, bl));
}

__global__ void k_counts(const int* __restrict__ seg, float* __restrict__ counts) {
    int i = blockIdx.x * blockDim.x + threadIdx.x;
    if (i < N_NODES) atomicAdd(&counts[seg[i]], 1.0f);
}

// ---------------- head: out[g] = (pooled[g]/count[g]) @ Wout + bout ----------
__global__ void k_out(const float* __restrict__ pooled, const float* __restrict__ counts,
                      const float* __restrict__ Wout, const float* __restrict__ bout,
                      float* __restrict__ out) {
    __shared__ float prow[D];
    int g = blockIdx.x;
    int t = threadIdx.x;
    if (t < D) prow[t] = pooled[(size_t)g * D + t] / fmaxf(counts[g], 1.0f);
    __syncthreads();
    if (t < N_TARGETS) {
        float acc = bout[t];
#pragma unroll
        for (int k = 0; k < D; ++k)
            acc = fmaf(prow[k], Wout[k * N_TARGETS + t], acc);
        out[g * N_TARGETS + t] = acc;
    }
}

// ---------------- driver ----------------

extern "C" void kernel_launch(void* const* d_in, const int* in_sizes, int n_in,
                              void* d_out, int out_size, void* d_ws, size_t ws_size,
                              hipStream_t stream) {
    const float* x    = (const float*)d_in[0];
    const float* W1   = (const float*)d_in[1];
    const float* b1   = (const float*)d_in[2];
    const float* W2   = (const float*)d_in[3];
    const float* b2   = (const float*)d_in[4];
    const float* W3   = (const float*)d_in[5];
    const float* b3   = (const float*)d_in[6];
    const float* Wout = (const float*)d_in[7];
    const float* bout = (const float*)d_in[8];
    const int*   eidx = (const int*)d_in[9];
    const int*   seg  = (const int*)d_in[10];
    const int* src = eidx;            // edge_index[0]
    const int* dst = eidx + N_EDGES;  // edge_index[1]
    float* out = (float*)d_out;

    // workspace layout (all 4B elems): total ~58.9 MB
    float* bufA   = (float*)d_ws;                  // 6,400,000
    float* bufB   = bufA + (size_t)N_NODES * D;    // 6,400,000
    int*   esrc   = (int*)(bufB + (size_t)N_NODES * D);  // 1,600,000
    float* dinv   = (float*)(esrc + N_EDGES);      // 100,000
    int*   degc   = (int*)(dinv + N_NODES);        // 100,000 (deg, then cursor)
    int*   base   = degc + N_NODES;                // 100,001 (+pad)
    int*   bsum   = base + N_NODES + 4;            // 512
    float* pooled = (float*)(bsum + 512);          // 32,768
    float* counts = pooled + N_GRAPHS * D;         // 512

    const int NB = (N_NODES + 255) / 256;  // 391

    // ---- CSR build (per-call; edge_index constant but no caching allowed) ----
    k_zero_i<<<NB, 256, 0, stream>>>(degc, N_NODES);
    k_deg<<<N_EDGES / 256, 256, 0, stream>>>(dst, degc);
    k_dinv<<<NB, 256, 0, stream>>>(degc, dinv);
    k_scan1<<<NB, 256, 0, stream>>>(degc, base, bsum);
    k_scan2<<<1, 512, 0, stream>>>(bsum, NB);
    k_scan3<<<NB, 256, 0, stream>>>(base, bsum, degc);
    k_fill<<<N_EDGES / 256, 256, 0, stream>>>(src, dst, base, degc, esrc);

    // ---- 3 GCN layers ----
    const int MMB = (N_NODES + 63) / 64;  // 1563
    k_mm<<<MMB, 256, 0, stream>>>(x, W1, dinv, bufA, 0);
    k_pull<<<N_NODES / 4, 256, 0, stream>>>(bufA, esrc, base, dinv, b1, bufB);
    k_mm<<<MMB, 256, 0, stream>>>(bufB, W2, dinv, bufA, 1);
    k_pull<<<N_NODES / 4, 256, 0, stream>>>(bufA, esrc, base, dinv, b2, bufB);
    k_mm<<<MMB, 256, 0, stream>>>(bufB, W3, dinv, bufA, 1);

    // ---- layer-3 pull fused with mean-pool accumulation ----
    k_zero_f<<<(N_GRAPHS * D + N_GRAPHS + 255) / 256, 256, 0, stream>>>(pooled, N_GRAPHS * D + N_GRAPHS);
    k_counts<<<NB, 256, 0, stream>>>(seg, counts);
    k_pull_pool<<<N_NODES / 4, 256, 0, stream>>>(bufA, esrc, base, dinv, b3, seg, pooled);

    k_out<<<N_GRAPHS, 128, 0, stream>>>(pooled, counts, Wout, bout, out);
}